// Round 9
// baseline (41.733 us; speedup 1.0000x reference)
//
#include <hip/hip_runtime.h>
#include <math.h>
#include <stdint.h>

// PedestrianDetector v14 = v13 with ONE variable changed: the XOR source
// swizzle is REMOVED from the staging path. Global loads are now textbook
// ascending-contiguous (lane i -> base + i*16B), identical to the v11 probe
// that read this exact buffer at ~6.3 TB/s.
//
// Unified theory (H6): the TA coalescer merges a wave's lane requests only in
// the ascending-contiguous pattern. Every slow variant (all 3.35 TB/s) issued
// either strided (v4) or XOR-permuted (v5/v6/v7/v13) lane->address maps ->
// ~4x request amplification -> request-rate-limited. The XOR was carried as a
// constant through every staged variant (rule-21 LDS-conflict fix), which is
// why all structural changes were neutral.
//
// The LDS bank conflict the XOR existed to fix is instead fixed by inter-row
// padding, which is legal with global_load_lds (it only needs a wave-uniform
// LDS base per instruction; the 1KB write itself stays linear): row stride =
// 257 floats -> read bank = (lane + 4*slot) & 31 -> 2 lanes/bank = free (m136).
// LDS = 2 buffers x 64 rows x 257 floats = 131,584 B dynamic (dyn launch path
// verified working in v13's rocprof: dispatches ran ped_det_kernel_dyn).
//
// Everything else v13-verbatim: 256 blocks x 1024 threads, 1 block/CU, 8
// chunks of 256 d, one global_load_lds dwordx4 per row per chunk (1KB span),
// counted vmcnt(4), scalar-W FMA loop, stride-15 reduce, stable top-3.

#define DCOLS  2048
#define RPB    64               // rows per block
#define NW     16               // waves per block (1024 threads)
#define PSTR   15               // partials row stride (odd -> conflict-free)
#define CCH    256              // chunk width in d (1KB per row per chunk)
#define NCH    (DCOLS / CCH)    // 8 chunks
#define ROWSTR 257              // LDS row stride in floats (+1 pad -> bank spread)
#define TILEP  (RPB * ROWSTR)   // 16448 floats per buffer
#define LDSB   (2 * TILEP * 4)  // 131,584 B dynamic

__global__ __launch_bounds__(1024, 4)
void ped_det_kernel_dyn(const float* __restrict__ feat,
                        const float* __restrict__ Wb,   // [2048][12]
                        const float* __restrict__ bb,   // [12]
                        const float* __restrict__ Wc,   // [2048][3]
                        const float* __restrict__ bc,   // [3]
                        float* __restrict__ out,
                        int nrows)
{
    extern __shared__ __align__(16) float lds[];   // [2][TILEP]
    float* P = &lds[0];   // [16][64][15] partials (15360 floats) alias, after loop
    float* S = P;         // [64][16] biased sums alias, behind further barrier

    const int t    = threadIdx.x;
    const int lane = t & 63;
    const int w    = t >> 6;
    const int wu   = __builtin_amdgcn_readfirstlane(w);  // wave-uniform -> scalar W

    const int rowBase = blockIdx.x * RPB;
    const float* fbase = feat + (size_t)rowBase * DCOLS;

    // stage: wave wu stages rows wu*4..wu*4+3; one instr = one row's full 1KB
    // span, lane i -> base + i*16B (ascending contiguous -- the probe pattern).
    // LDS dest: wave-uniform base r*ROWSTR, written linearly by HW.
    auto STAGE = [&](int c, int p) {
#pragma unroll
        for (int i = 0; i < 4; ++i) {
            const int r = wu * 4 + i;
            const float* g = fbase + (size_t)r * DCOLS + c * CCH + (lane << 2);
            const float* l = &lds[(size_t)p * TILEP + r * ROWSTR];
            __builtin_amdgcn_global_load_lds(
                (const __attribute__((address_space(1))) void*)g,
                (__attribute__((address_space(3))) void*)l, 16, 0, 0);
        }
    };

    float acc[15];
#pragma unroll
    for (int j = 0; j < 15; ++j) acc[j] = 0.0f;

    STAGE(0, 0);

    for (int c = 0; c < NCH; ++c) {
        if (c + 1 < NCH) {
            STAGE(c + 1, (c + 1) & 1);
            asm volatile("s_waitcnt vmcnt(4)" ::: "memory");  // retire chunk c only
        } else {
            asm volatile("s_waitcnt vmcnt(0)" ::: "memory");
        }
        asm volatile("s_barrier" ::: "memory");   // all rows of chunk c resident

        const float* buf = &lds[(size_t)(c & 1) * TILEP];
        // wave wu consumes content slots s = wu*4+q (wave-uniform d-slice);
        // row = lane. Padded stride: bank = (lane + 4s) & 31 -> 2-way = free.
#pragma unroll
        for (int q = 0; q < 4; ++q) {
            const int s = wu * 4 + q;
            const float4 f = *(const float4*)(buf + (size_t)lane * ROWSTR + s * 4);
            const int du = c * CCH + wu * 16 + q * 4;       // wave-uniform d
            const float* __restrict__ wbp = Wb + (size_t)du * 12;
            const float* __restrict__ wcp = Wc + (size_t)du * 3;
            const float fv[4] = { f.x, f.y, f.z, f.w };
#pragma unroll
            for (int jj = 0; jj < 4; ++jj) {
                const float v = fv[jj];
                acc[0]  += v * wbp[jj * 12 + 0];
                acc[1]  += v * wbp[jj * 12 + 1];
                acc[2]  += v * wbp[jj * 12 + 2];
                acc[3]  += v * wbp[jj * 12 + 3];
                acc[4]  += v * wbp[jj * 12 + 4];
                acc[5]  += v * wbp[jj * 12 + 5];
                acc[6]  += v * wbp[jj * 12 + 6];
                acc[7]  += v * wbp[jj * 12 + 7];
                acc[8]  += v * wbp[jj * 12 + 8];
                acc[9]  += v * wbp[jj * 12 + 9];
                acc[10] += v * wbp[jj * 12 + 10];
                acc[11] += v * wbp[jj * 12 + 11];
                acc[12] += v * wcp[jj * 3 + 0];
                acc[13] += v * wcp[jj * 3 + 1];
                acc[14] += v * wcp[jj * 3 + 2];
            }
        }

        // reads must be in registers before this buffer is restaged next iter
        asm volatile("s_waitcnt lgkmcnt(0)" ::: "memory");
        asm volatile("s_barrier" ::: "memory");
    }

    // ---- reduce + epilogue (v6/v7/v13 verbatim) ----
    {
        float* pp = &P[(wu * RPB + lane) * PSTR];
#pragma unroll
        for (int j = 0; j < 15; ++j) pp[j] = acc[j];
    }
    __syncthreads();

    float sval = 0.0f;
    int rl = 0, jj = 0;
    if (t < RPB * 15) {
        rl = t / 15;
        jj = t % 15;
        float s = 0.0f;
#pragma unroll
        for (int w2 = 0; w2 < NW; ++w2)
            s += P[(w2 * RPB + rl) * PSTR + jj];
        s += (jj < 12) ? bb[jj] : bc[jj - 12];
        sval = s;
    }
    __syncthreads();

    if (t < RPB * 15)
        S[rl * 16 + jj] = sval;
    __syncthreads();

    if (t < RPB) {
        const int r2 = t;
        float box[12];
#pragma unroll
        for (int j = 0; j < 12; ++j) box[j] = S[r2 * 16 + j];
        float conf[3];
#pragma unroll
        for (int a = 0; a < 3; ++a)
            conf[a] = 1.0f / (1.0f + __expf(-S[r2 * 16 + 12 + a]));

        int i0 = 0; float m0 = conf[0];
        if (conf[1] > m0) { i0 = 1; m0 = conf[1]; }
        if (conf[2] > m0) { i0 = 2; m0 = conf[2]; }
        const int ra = (i0 == 0) ? 1 : 0;
        const int rb = (i0 == 2) ? 1 : 2;
        int i1, i2;
        if (conf[rb] > conf[ra]) { i1 = rb; i2 = ra; }
        else                     { i1 = ra; i2 = rb; }
        const int idx[3] = { i0, i1, i2 };

        const int ro = blockIdx.x * RPB + r2;
        float* boxout  = out + (size_t)ro * 12;
        float* confout = out + (size_t)nrows * 12 + (size_t)ro * 3;
        float* valout  = out + (size_t)nrows * 15 + (size_t)ro * 3;
#pragma unroll
        for (int sl = 0; sl < 3; ++sl) {
            const int   a   = idx[sl];
            const float cv  = conf[a];
            const bool  vld = cv > 0.5f;
            float4 bx;
            bx.x = vld ? box[a * 4 + 0] : 0.0f;
            bx.y = vld ? box[a * 4 + 1] : 0.0f;
            bx.z = vld ? box[a * 4 + 2] : 0.0f;
            bx.w = vld ? box[a * 4 + 3] : 0.0f;
            *(float4*)(boxout + sl * 4) = bx;
            confout[sl] = cv;
            valout[sl]  = vld ? 1.0f : 0.0f;
        }
    }
}

extern "C" void kernel_launch(void* const* d_in, const int* in_sizes, int n_in,
                              void* d_out, int out_size, void* d_ws, size_t ws_size,
                              hipStream_t stream) {
    const float* feat = (const float*)d_in[0];
    const float* Wb   = (const float*)d_in[1];
    const float* bb   = (const float*)d_in[2];
    const float* Wc   = (const float*)d_in[3];
    const float* bc   = (const float*)d_in[4];
    float* out = (float*)d_out;

    const int nrows   = in_sizes[0] / DCOLS;   // 16384
    const int nblocks = nrows / RPB;           // 256 -> 1 block/CU

    static int dyn_ok = -1;   // one-time attribute setup (host-side, capture-safe)
    if (dyn_ok < 0) {
        hipError_t e = hipFuncSetAttribute(
            (const void*)ped_det_kernel_dyn,
            hipFuncAttributeMaxDynamicSharedMemorySize, LDSB);
        dyn_ok = (e == hipSuccess) ? 1 : 0;
    }

    ped_det_kernel_dyn<<<dim3(nblocks), dim3(1024), LDSB, stream>>>(
        feat, Wb, bb, Wc, bc, out, nrows);
}